// Round 5
// baseline (98.389 us; speedup 1.0000x reference)
//
#include <hip/hip_runtime.h>

// Fused cascaded-biquad IIR (DF2T) via linear state-space chunking.
// One block per batch row (512 blocks x 512 threads); each thread owns a
// 64-step chunk held in 16 NAMED float4 registers.
//   - stage-in/out through LDS with 128B-line-dense global access
//   - XOR-swizzled LDS slots (conflict-free transposed reads)
//   - wave 0 builds M_d = (A^64)^(2^d) in-register via __shfl
//   - block-local Kogge-Stone affine scan (9 levels, W double-buffer aliased
//     into the tile buffer, 1 barrier per level)

namespace {
constexpr int NS     = 4;
constexpr int BATCH  = 512;
constexpr int TLEN   = 32768;        // 2^15
constexpr int NSTATE = 8;
constexpr int NTHR   = 512;          // threads/block = chunks/batch
constexpr int LOG2P  = 9;            // scan levels over 512 chunks
constexpr int LOG2L  = 6;            // log2(64 steps per chunk)
}

__device__ __forceinline__ void load_coefs(const float* __restrict__ bc,
                                           const float* __restrict__ ac,
                                           float b0[NS], float b1[NS], float b2[NS],
                                           float a1[NS], float a2[NS]) {
#pragma unroll
  for (int k = 0; k < NS; ++k) {
    b0[k] = bc[3 * k];
    b1[k] = bc[3 * k + 1];
    b2[k] = bc[3 * k + 2];
    a1[k] = ac[2 * k];
    a2[k] = ac[2 * k + 1];
  }
}

// One time-step through the 4-section cascade (matches reference exactly).
__device__ __forceinline__ float step_cascade(float sig,
                                              const float b0[NS], const float b1[NS],
                                              const float b2[NS], const float a1[NS],
                                              const float a2[NS],
                                              float s1[NS], float s2[NS]) {
#pragma unroll
  for (int k = 0; k < NS; ++k) {
    float y = fmaf(b0[k], sig, s1[k]);
    s1[k]   = fmaf(-a1[k], y, fmaf(b1[k], sig, s2[k]));
    s2[k]   = fmaf(-a2[k], y, b2[k] * sig);
    sig = y;
  }
  return sig;
}

#define CO b0, b1, b2, a1, a2

__device__ __forceinline__ void adv4(const float4 u,
                                     const float b0[NS], const float b1[NS],
                                     const float b2[NS], const float a1[NS],
                                     const float a2[NS], float s1[NS], float s2[NS]) {
  (void)step_cascade(u.x, CO, s1, s2);
  (void)step_cascade(u.y, CO, s1, s2);
  (void)step_cascade(u.z, CO, s1, s2);
  (void)step_cascade(u.w, CO, s1, s2);
}

__device__ __forceinline__ float4 out4(const float4 u,
                                       const float b0[NS], const float b1[NS],
                                       const float b2[NS], const float a1[NS],
                                       const float a2[NS], float s1[NS], float s2[NS]) {
  float4 y;
  y.x = step_cascade(u.x, CO, s1, s2);
  y.y = step_cascade(u.y, CO, s1, s2);
  y.z = step_cascade(u.z, CO, s1, s2);
  y.w = step_cascade(u.w, CO, s1, s2);
  return y;
}

__global__ __launch_bounds__(NTHR, 4) void k_fused(const float* __restrict__ x,
                                                   const float* __restrict__ bc,
                                                   const float* __restrict__ ac,
                                                   float* __restrict__ out) {
  // 64 KiB tile buffer; scan W double-buffer (2 x 512 x 9 floats) aliases it.
  __shared__ float4 buf[4096];
  __shared__ float  Ms[LOG2P][64];

  const int t = threadIdx.x;
  const float4* __restrict__ gsrc =
      reinterpret_cast<const float4*>(x) + (size_t)blockIdx.x * (TLEN / 4);
  float4* __restrict__ gdst =
      reinterpret_cast<float4*>(out) + (size_t)blockIdx.x * (TLEN / 4);

  float b0[NS], b1[NS], b2[NS], a1[NS], a2[NS];
  load_coefs(bc, ac, b0, b1, b2, a1, a2);

  // Staging index math (128B-dense): per j, this thread handles chunk
  // c = (t>>3)+64j, in-chunk float4 q0 = t&7. Global f4 = c*16 + tile*8 + q0
  // -> 8 consecutive lanes cover one full 128B line. LDS slot is XOR-swizzled.
  const int q0 = t & 7;
  const int cb = t >> 3;           // + 64*j
  const int myswz = t & 7;         // own chunk c = t -> c&7 = t&7
  const int rbase = t * 8;

  float4 st[8];  // staging regs (literal-indexed only)
  // ---- issue tile0 loads
#pragma unroll
  for (int j = 0; j < 8; ++j) st[j] = gsrc[(cb + 64 * j) * 16 + q0];

  // ---- wave 0: build Ms[d] = (A^64)^(2^d) in-register via __shfl
  if (t < 64) {
    const int r = t >> 3, c = t & 7;
    float p1[NS] = {0.f, 0.f, 0.f, 0.f};
    float p2[NS] = {0.f, 0.f, 0.f, 0.f};
    if (c & 1) p2[c >> 1] = 1.0f; else p1[c >> 1] = 1.0f;
    (void)step_cascade(0.0f, CO, p1, p2);
    float m = (r & 1) ? p2[r >> 1] : p1[r >> 1];  // A element (r,c)
    for (int it = 0; it < LOG2L + LOG2P - 1; ++it) {  // 14 squarings
      float acc = 0.0f;
#pragma unroll
      for (int k = 0; k < NSTATE; ++k)
        acc = fmaf(__shfl(m, r * 8 + k), __shfl(m, k * 8 + c), acc);
      m = acc;
      if (it >= LOG2L - 1) Ms[it - (LOG2L - 1)][t] = m;
    }
  }

  // ---- write tile0 to LDS (transposed + swizzled), issue tile1 loads
#pragma unroll
  for (int j = 0; j < 8; ++j) {
    const int c = cb + 64 * j;
    buf[c * 8 + (q0 ^ (c & 7))] = st[j];
  }
#pragma unroll
  for (int j = 0; j < 8; ++j) st[j] = gsrc[(cb + 64 * j) * 16 + 8 + q0];
  __syncthreads();

  float s1[NS] = {0.f, 0.f, 0.f, 0.f};
  float s2[NS] = {0.f, 0.f, 0.f, 0.f};
  float4 x0, x1, x2, x3, x4, x5, x6, x7, x8, x9, x10, x11, x12, x13, x14, x15;

#define RD(Q) buf[rbase + ((Q) ^ myswz)]
  // ---- phase A, tile0 (f4 0..7)
  x0 = RD(0); adv4(x0, CO, s1, s2);
  x1 = RD(1); adv4(x1, CO, s1, s2);
  x2 = RD(2); adv4(x2, CO, s1, s2);
  x3 = RD(3); adv4(x3, CO, s1, s2);
  x4 = RD(4); adv4(x4, CO, s1, s2);
  x5 = RD(5); adv4(x5, CO, s1, s2);
  x6 = RD(6); adv4(x6, CO, s1, s2);
  x7 = RD(7); adv4(x7, CO, s1, s2);
  __syncthreads();
  // ---- stage tile1, phase A tile1 (f4 8..15)
#pragma unroll
  for (int j = 0; j < 8; ++j) {
    const int c = cb + 64 * j;
    buf[c * 8 + (q0 ^ (c & 7))] = st[j];
  }
  __syncthreads();
  x8  = RD(0); adv4(x8,  CO, s1, s2);
  x9  = RD(1); adv4(x9,  CO, s1, s2);
  x10 = RD(2); adv4(x10, CO, s1, s2);
  x11 = RD(3); adv4(x11, CO, s1, s2);
  x12 = RD(4); adv4(x12, CO, s1, s2);
  x13 = RD(5); adv4(x13, CO, s1, s2);
  x14 = RD(6); adv4(x14, CO, s1, s2);
  x15 = RD(7); adv4(x15, CO, s1, s2);

  // ---- block-local Kogge-Stone affine scan (W aliases buf; 1 barrier/level)
  float w[NSTATE];
#pragma unroll
  for (int k = 0; k < NS; ++k) { w[2 * k] = s1[k]; w[2 * k + 1] = s2[k]; }

  float* W0 = reinterpret_cast<float*>(buf);
  float* W1 = W0 + 4608;  // 512*9
  __syncthreads();        // tile1 LDS reads done; buf reusable
#pragma unroll
  for (int r = 0; r < NSTATE; ++r) W0[t * 9 + r] = w[r];
  __syncthreads();
#pragma unroll
  for (int d = 0; d < LOG2P; ++d) {
    const float* Wsrc = (d & 1) ? W1 : W0;
    float* Wdst       = (d & 1) ? W0 : W1;
    if (t >= (1 << d)) {
      const int src = (t - (1 << d)) * 9;
      float prev[NSTATE];
#pragma unroll
      for (int r = 0; r < NSTATE; ++r) prev[r] = Wsrc[src + r];
#pragma unroll
      for (int r = 0; r < NSTATE; ++r) {
        float acc = w[r];
#pragma unroll
        for (int k = 0; k < NSTATE; ++k)
          acc = fmaf(Ms[d][r * 8 + k], prev[k], acc);  // uniform addr: broadcast
        w[r] = acc;
      }
    }
#pragma unroll
    for (int r = 0; r < NSTATE; ++r) Wdst[t * 9 + r] = w[r];
    __syncthreads();
  }
  // exclusive shift: final inclusive values live in W1 (d=8 wrote Wdst=W1)
  if (t == 0) {
#pragma unroll
    for (int k = 0; k < NS; ++k) { s1[k] = 0.0f; s2[k] = 0.0f; }
  } else {
    const int src = (t - 1) * 9;
#pragma unroll
    for (int k = 0; k < NS; ++k) {
      s1[k] = W1[src + 2 * k];
      s2[k] = W1[src + 2 * k + 1];
    }
  }
  __syncthreads();  // exclusive reads done before buf overwrite

  // ---- phase B, tile0: replay f4 0..7, stage out 128B-dense
#define WR(Q, XV) buf[rbase + ((Q) ^ myswz)] = out4((XV), CO, s1, s2)
  WR(0, x0); WR(1, x1); WR(2, x2); WR(3, x3);
  WR(4, x4); WR(5, x5); WR(6, x6); WR(7, x7);
  __syncthreads();
#pragma unroll
  for (int j = 0; j < 8; ++j) {
    const int c = cb + 64 * j;
    gdst[c * 16 + q0] = buf[c * 8 + (q0 ^ (c & 7))];
  }
  __syncthreads();
  // ---- phase B, tile1
  WR(0, x8);  WR(1, x9);  WR(2, x10); WR(3, x11);
  WR(4, x12); WR(5, x13); WR(6, x14); WR(7, x15);
  __syncthreads();
#pragma unroll
  for (int j = 0; j < 8; ++j) {
    const int c = cb + 64 * j;
    gdst[c * 16 + 8 + q0] = buf[c * 8 + (q0 ^ (c & 7))];
  }
#undef RD
#undef WR
}

extern "C" void kernel_launch(void* const* d_in, const int* in_sizes, int n_in,
                              void* d_out, int out_size, void* d_ws, size_t ws_size,
                              hipStream_t stream) {
  const float* x  = (const float*)d_in[0];  // (B, T, 1)
  const float* bc = (const float*)d_in[1];  // (NS, 3)
  const float* ac = (const float*)d_in[2];  // (NS, 2)
  float* out = (float*)d_out;               // (B, T, 1)

  k_fused<<<BATCH, NTHR, 0, stream>>>(x, bc, ac, out);
}

// Round 6
// 96.324 us; speedup vs baseline: 1.0214x; 1.0214x over previous
//
#include <hip/hip_runtime.h>

// Cascaded biquad IIR (DF2T) via linear state-space chunking. 3 kernels:
//   1) k_chunk_state: per-chunk final state from zero init
//   2) k_scan_par:    Kogge-Stone affine scan across chunks (wave 0 builds
//                     the A^L powers in-register via __shfl)
//   3) k_chunk_out:   replay each chunk from its exact initial state
// Staging: 128B-dense global access (8 lanes cover one full 128B line),
// XOR-swizzled LDS transpose tiles (conflict-free both directions).
// No forced launch_bounds occupancy -> no VGPR spills (R5 lesson).

namespace {
constexpr int NS     = 4;
constexpr int BATCH  = 512;
constexpr int TLEN   = 32768;   // 2^15
constexpr int NSTATE = 8;
}

__device__ __forceinline__ void load_coefs(const float* __restrict__ bc,
                                           const float* __restrict__ ac,
                                           float b0[NS], float b1[NS], float b2[NS],
                                           float a1[NS], float a2[NS]) {
#pragma unroll
  for (int k = 0; k < NS; ++k) {
    b0[k] = bc[3 * k];
    b1[k] = bc[3 * k + 1];
    b2[k] = bc[3 * k + 2];
    a1[k] = ac[2 * k];
    a2[k] = ac[2 * k + 1];
  }
}

// One time-step through the 4-section cascade (matches reference exactly).
__device__ __forceinline__ float step_cascade(float sig,
                                              const float b0[NS], const float b1[NS],
                                              const float b2[NS], const float a1[NS],
                                              const float a2[NS],
                                              float s1[NS], float s2[NS]) {
#pragma unroll
  for (int k = 0; k < NS; ++k) {
    float y = fmaf(b0[k], sig, s1[k]);
    s1[k]   = fmaf(-a1[k], y, fmaf(b1[k], sig, s2[k]));
    s2[k]   = fmaf(-a2[k], y, b2[k] * sig);
    sig = y;
  }
  return sig;
}

#define CO b0, b1, b2, a1, a2

__device__ __forceinline__ void adv4(const float4 u,
                                     const float b0[NS], const float b1[NS],
                                     const float b2[NS], const float a1[NS],
                                     const float a2[NS], float s1[NS], float s2[NS]) {
  (void)step_cascade(u.x, CO, s1, s2);
  (void)step_cascade(u.y, CO, s1, s2);
  (void)step_cascade(u.z, CO, s1, s2);
  (void)step_cascade(u.w, CO, s1, s2);
}

__device__ __forceinline__ float4 out4(const float4 u,
                                       const float b0[NS], const float b1[NS],
                                       const float b2[NS], const float a1[NS],
                                       const float a2[NS], float s1[NS], float s2[NS]) {
  float4 y;
  y.x = step_cascade(u.x, CO, s1, s2);
  y.y = step_cascade(u.y, CO, s1, s2);
  y.z = step_cascade(u.z, CO, s1, s2);
  y.w = step_cascade(u.w, CO, s1, s2);
  return y;
}

// ---------------------------------------------------------------------------
// Phase 1: 256 threads/block own 256 consecutive chunks. Tiles of 32 steps
// (8 float4 = 128B per chunk) staged via swizzled LDS transpose.
template <int P>
__global__ __launch_bounds__(256) void k_chunk_state(const float* __restrict__ x,
                                                     const float* __restrict__ bc,
                                                     const float* __restrict__ ac,
                                                     float* __restrict__ vbuf) {
  constexpr int L   = TLEN / P;
  constexpr int LQ  = L / 4;      // float4 per chunk
  constexpr int NTL = LQ / 8;     // tiles (8 f4 per chunk per tile)
  __shared__ float4 buf[2048];    // 256 chunks * 8 f4 = 32 KiB

  const int t    = threadIdx.x;
  const int q0   = t & 7;
  const int crow = t >> 3;        // + 32*j
  const int swz  = t & 7;         // own chunk c=t -> c&7

  float b0[NS], b1[NS], b2[NS], a1[NS], a2[NS];
  load_coefs(bc, ac, b0, b1, b2, a1, a2);

  const float4* __restrict__ gsrc =
      reinterpret_cast<const float4*>(x) + (size_t)blockIdx.x * 256 * LQ;

  float s1[NS] = {0.f, 0.f, 0.f, 0.f};
  float s2[NS] = {0.f, 0.f, 0.f, 0.f};

  float4 ld[8];
#pragma unroll
  for (int j = 0; j < 8; ++j)
    ld[j] = gsrc[(crow + 32 * j) * LQ + q0];

  for (int tile = 0; tile < NTL; ++tile) {
    if (tile) __syncthreads();          // prior tile's reads complete
#pragma unroll
    for (int j = 0; j < 8; ++j) {
      const int c = crow + 32 * j;
      buf[c * 8 + (q0 ^ (c & 7))] = ld[j];
    }
    if (tile + 1 < NTL) {               // prefetch next tile (in flight over compute)
#pragma unroll
      for (int j = 0; j < 8; ++j)
        ld[j] = gsrc[(crow + 32 * j) * LQ + (tile + 1) * 8 + q0];
    }
    __syncthreads();
#pragma unroll
    for (int q = 0; q < 8; ++q)
      adv4(buf[t * 8 + (q ^ swz)], CO, s1, s2);
  }

  float* __restrict__ vp = vbuf + ((size_t)blockIdx.x * 256 + t) * NSTATE;
  *reinterpret_cast<float4*>(vp)     = make_float4(s1[0], s2[0], s1[1], s2[1]);
  *reinterpret_cast<float4*>(vp + 4) = make_float4(s1[2], s2[2], s1[3], s2[3]);
}

// ---------------------------------------------------------------------------
// Phase 2: Kogge-Stone affine scan. Wave 0 builds Ms[d] = (A^L)^(2^d)
// in-register via __shfl (14 squarings of the 8x8, one element per lane).
template <int P, int LOG2P, int LOG2L>
__global__ void k_scan_par(const float* __restrict__ bc,
                           const float* __restrict__ ac,
                           float* __restrict__ vbuf) {
  constexpr int THREADS = (P > 256) ? P : 256;
  constexpr int BPB     = THREADS / P;
  __shared__ float Ms[LOG2P][64];
  __shared__ float W[THREADS][NSTATE + 1];  // stride 9: 2-way alias (free)

  const int t = threadIdx.x;

  if (t < 64) {
    float b0[NS], b1[NS], b2[NS], a1[NS], a2[NS];
    load_coefs(bc, ac, b0, b1, b2, a1, a2);
    const int r = t >> 3, c = t & 7;
    float p1[NS] = {0.f, 0.f, 0.f, 0.f};
    float p2[NS] = {0.f, 0.f, 0.f, 0.f};
    if (c & 1) p2[c >> 1] = 1.0f; else p1[c >> 1] = 1.0f;
    (void)step_cascade(0.0f, CO, p1, p2);
    float m = (r & 1) ? p2[r >> 1] : p1[r >> 1];  // A element (r,c)
    for (int it = 0; it < LOG2L + LOG2P - 1; ++it) {
      float acc = 0.0f;
#pragma unroll
      for (int k = 0; k < NSTATE; ++k)
        acc = fmaf(__shfl(m, r * 8 + k), __shfl(m, k * 8 + c), acc);
      m = acc;
      if (it >= LOG2L - 1) Ms[it - (LOG2L - 1)][t] = m;
    }
  }

  const int sub = t / P;
  const int ci  = t % P;
  float* __restrict__ vp =
      vbuf + (((size_t)blockIdx.x * BPB + sub) * P + ci) * NSTATE;

  float w[NSTATE];
  {
    const float4 va = *reinterpret_cast<const float4*>(vp);
    const float4 vb = *reinterpret_cast<const float4*>(vp + 4);
    w[0] = va.x; w[1] = va.y; w[2] = va.z; w[3] = va.w;
    w[4] = vb.x; w[5] = vb.y; w[6] = vb.z; w[7] = vb.w;
  }
  __syncthreads();  // Ms ready

  for (int d = 0; d < LOG2P; ++d) {
#pragma unroll
    for (int r = 0; r < NSTATE; ++r) W[t][r] = w[r];
    __syncthreads();
    if (ci >= (1 << d)) {
      const int src = t - (1 << d);
      float prev[NSTATE];
#pragma unroll
      for (int r = 0; r < NSTATE; ++r) prev[r] = W[src][r];
#pragma unroll
      for (int r = 0; r < NSTATE; ++r) {
        float acc = w[r];
#pragma unroll
        for (int k = 0; k < NSTATE; ++k)
          acc = fmaf(Ms[d][r * 8 + k], prev[k], acc);  // uniform addr: broadcast
        w[r] = acc;
      }
    }
    __syncthreads();
  }

  // exclusive shift: s_init(i) = (i==0 ? 0 : w_{i-1})
#pragma unroll
  for (int r = 0; r < NSTATE; ++r) W[t][r] = w[r];
  __syncthreads();
  float s[NSTATE];
  if (ci == 0) {
#pragma unroll
    for (int r = 0; r < NSTATE; ++r) s[r] = 0.0f;
  } else {
#pragma unroll
    for (int r = 0; r < NSTATE; ++r) s[r] = W[t - 1][r];
  }
  *reinterpret_cast<float4*>(vp)     = make_float4(s[0], s[1], s[2], s[3]);
  *reinterpret_cast<float4*>(vp + 4) = make_float4(s[4], s[5], s[6], s[7]);
}

// ---------------------------------------------------------------------------
// Phase 3: replay from exact init. Same swizzled tiles; compute writes back
// in-place (per-thread slots), then coalesced stage-out.
template <int P>
__global__ __launch_bounds__(256) void k_chunk_out(const float* __restrict__ x,
                                                   const float* __restrict__ bc,
                                                   const float* __restrict__ ac,
                                                   const float* __restrict__ sbuf,
                                                   float* __restrict__ out) {
  constexpr int L   = TLEN / P;
  constexpr int LQ  = L / 4;
  constexpr int NTL = LQ / 8;
  __shared__ float4 buf[2048];    // 32 KiB

  const int t    = threadIdx.x;
  const int q0   = t & 7;
  const int crow = t >> 3;
  const int swz  = t & 7;

  float b0[NS], b1[NS], b2[NS], a1[NS], a2[NS];
  load_coefs(bc, ac, b0, b1, b2, a1, a2);

  const float* __restrict__ sp =
      sbuf + ((size_t)blockIdx.x * 256 + t) * NSTATE;
  const float4 sa = *reinterpret_cast<const float4*>(sp);
  const float4 sb = *reinterpret_cast<const float4*>(sp + 4);
  float s1[NS] = {sa.x, sa.z, sb.x, sb.z};
  float s2[NS] = {sa.y, sa.w, sb.y, sb.w};

  const float4* __restrict__ gsrc =
      reinterpret_cast<const float4*>(x) + (size_t)blockIdx.x * 256 * LQ;
  float4* __restrict__ gdst =
      reinterpret_cast<float4*>(out) + (size_t)blockIdx.x * 256 * LQ;

  float4 ld[8];
#pragma unroll
  for (int j = 0; j < 8; ++j)
    ld[j] = gsrc[(crow + 32 * j) * LQ + q0];

  for (int tile = 0; tile < NTL; ++tile) {
    if (tile) __syncthreads();          // prior stage-out reads complete
#pragma unroll
    for (int j = 0; j < 8; ++j) {
      const int c = crow + 32 * j;
      buf[c * 8 + (q0 ^ (c & 7))] = ld[j];
    }
    if (tile + 1 < NTL) {
#pragma unroll
      for (int j = 0; j < 8; ++j)
        ld[j] = gsrc[(crow + 32 * j) * LQ + (tile + 1) * 8 + q0];
    }
    __syncthreads();
#pragma unroll
    for (int q = 0; q < 8; ++q) {
      const int slot = t * 8 + (q ^ swz);
      buf[slot] = out4(buf[slot], CO, s1, s2);  // in-place: own slots only
    }
    __syncthreads();
#pragma unroll
    for (int j = 0; j < 8; ++j) {
      const int c = crow + 32 * j;
      gdst[c * LQ + tile * 8 + q0] = buf[c * 8 + (q0 ^ (c & 7))];
    }
  }
}

// ---------------------------------------------------------------------------
// Fallback (ws too small): one thread per batch, fully sequential but correct.
__global__ void k_naive(const float* __restrict__ x, const float* __restrict__ bc,
                        const float* __restrict__ ac, float* __restrict__ out) {
  const int bi = blockIdx.x * blockDim.x + threadIdx.x;
  if (bi >= BATCH) return;
  float b0[NS], b1[NS], b2[NS], a1[NS], a2[NS];
  load_coefs(bc, ac, b0, b1, b2, a1, a2);
  float s1[NS] = {0.f, 0.f, 0.f, 0.f};
  float s2[NS] = {0.f, 0.f, 0.f, 0.f};
  const float* __restrict__ xp = x + (size_t)bi * TLEN;
  float* __restrict__ op       = out + (size_t)bi * TLEN;
  for (int t = 0; t < TLEN; t += 4) {
    const float4 xv = *reinterpret_cast<const float4*>(xp + t);
    float4 y = out4(xv, CO, s1, s2);
    *reinterpret_cast<float4*>(op + t) = y;
  }
}

// ---------------------------------------------------------------------------
template <int P, int LOG2P, int LOG2L>
static void run_pipeline(const float* x, const float* bc, const float* ac,
                         float* out, void* d_ws, hipStream_t stream) {
  constexpr int THREADS = (P > 256) ? P : 256;
  float* vbuf = (float*)d_ws;  // BATCH*P*8 floats

  k_chunk_state<P><<<(BATCH * P) / 256, 256, 0, stream>>>(x, bc, ac, vbuf);
  k_scan_par<P, LOG2P, LOG2L>
      <<<(BATCH * P) / THREADS, THREADS, 0, stream>>>(bc, ac, vbuf);
  k_chunk_out<P><<<(BATCH * P) / 256, 256, 0, stream>>>(x, bc, ac, vbuf, out);
}

extern "C" void kernel_launch(void* const* d_in, const int* in_sizes, int n_in,
                              void* d_out, int out_size, void* d_ws, size_t ws_size,
                              hipStream_t stream) {
  const float* x  = (const float*)d_in[0];  // (B, T, 1)
  const float* bc = (const float*)d_in[1];  // (NS, 3)
  const float* ac = (const float*)d_in[2];  // (NS, 2)
  float* out = (float*)d_out;               // (B, T, 1)

  const size_t need512 = (size_t)BATCH * 512 * NSTATE * sizeof(float);
  const size_t need256 = (size_t)BATCH * 256 * NSTATE * sizeof(float);
  const size_t need128 = (size_t)BATCH * 128 * NSTATE * sizeof(float);

  if (ws_size >= need512) {
    run_pipeline<512, 9, 6>(x, bc, ac, out, d_ws, stream);
  } else if (ws_size >= need256) {
    run_pipeline<256, 8, 7>(x, bc, ac, out, d_ws, stream);
  } else if (ws_size >= need128) {
    run_pipeline<128, 7, 8>(x, bc, ac, out, d_ws, stream);
  } else {
    k_naive<<<(BATCH + 255) / 256, 256, 0, stream>>>(x, bc, ac, out);
  }
}

// Round 7
// 59.056 us; speedup vs baseline: 1.6660x; 1.6311x over previous
//
#include <hip/hip_runtime.h>

// Cascaded biquad IIR (DF2T) via linear state-space chunking. 3 kernels:
//   1) k_chunk_state: per-chunk final state from zero init
//   2) k_scan_par:    Kogge-Stone affine scan across chunks (wave 0 builds
//                     the A^L powers in-register via __shfl)
//   3) k_chunk_out:   replay each chunk from its exact initial state
// R7: copy-kernel memory shape — fully linear per-wave-contiguous global
// access, one deep 16-load burst per thread (64KB/block in flight), single
// barrier pair, 64KB XOR-swizzled LDS transpose (2-way aliasing = free).

namespace {
constexpr int NS     = 4;
constexpr int BATCH  = 512;
constexpr int TLEN   = 32768;   // 2^15
constexpr int NSTATE = 8;
constexpr int P      = 512;     // chunks per batch
constexpr int L      = TLEN / P;   // 64 steps
constexpr int LQ     = L / 4;      // 16 float4 per chunk
constexpr int LOG2P  = 9;
constexpr int LOG2L  = 6;
}

__device__ __forceinline__ void load_coefs(const float* __restrict__ bc,
                                           const float* __restrict__ ac,
                                           float b0[NS], float b1[NS], float b2[NS],
                                           float a1[NS], float a2[NS]) {
#pragma unroll
  for (int k = 0; k < NS; ++k) {
    b0[k] = bc[3 * k];
    b1[k] = bc[3 * k + 1];
    b2[k] = bc[3 * k + 2];
    a1[k] = ac[2 * k];
    a2[k] = ac[2 * k + 1];
  }
}

// One time-step through the 4-section cascade (matches reference exactly).
__device__ __forceinline__ float step_cascade(float sig,
                                              const float b0[NS], const float b1[NS],
                                              const float b2[NS], const float a1[NS],
                                              const float a2[NS],
                                              float s1[NS], float s2[NS]) {
#pragma unroll
  for (int k = 0; k < NS; ++k) {
    float y = fmaf(b0[k], sig, s1[k]);
    s1[k]   = fmaf(-a1[k], y, fmaf(b1[k], sig, s2[k]));
    s2[k]   = fmaf(-a2[k], y, b2[k] * sig);
    sig = y;
  }
  return sig;
}

#define CO b0, b1, b2, a1, a2

__device__ __forceinline__ void adv4(const float4 u,
                                     const float b0[NS], const float b1[NS],
                                     const float b2[NS], const float a1[NS],
                                     const float a2[NS], float s1[NS], float s2[NS]) {
  (void)step_cascade(u.x, CO, s1, s2);
  (void)step_cascade(u.y, CO, s1, s2);
  (void)step_cascade(u.z, CO, s1, s2);
  (void)step_cascade(u.w, CO, s1, s2);
}

__device__ __forceinline__ float4 out4(const float4 u,
                                       const float b0[NS], const float b1[NS],
                                       const float b2[NS], const float a1[NS],
                                       const float a2[NS], float s1[NS], float s2[NS]) {
  float4 y;
  y.x = step_cascade(u.x, CO, s1, s2);
  y.y = step_cascade(u.y, CO, s1, s2);
  y.z = step_cascade(u.z, CO, s1, s2);
  y.w = step_cascade(u.w, CO, s1, s2);
  return y;
}

// LDS slot for (chunk c within block, float4 index q): XOR swizzle makes both
// the linear staging writes and the per-chunk compute reads 2-way (free).
__device__ __forceinline__ int slot_of(int c, int q) {
  return c * LQ + (q ^ (c & (LQ - 1)));
}

// ---------------------------------------------------------------------------
// Phase 1: block owns 256 consecutive chunks (64KB). Burst-load the whole
// region linearly, LDS-transpose, one barrier, compute chunk final states.
__global__ __launch_bounds__(256) void k_chunk_state(const float* __restrict__ x,
                                                     const float* __restrict__ bc,
                                                     const float* __restrict__ ac,
                                                     float* __restrict__ vbuf) {
  __shared__ float4 sbuf[256 * LQ];  // 64 KiB

  const int t = threadIdx.x;
  float b0[NS], b1[NS], b2[NS], a1[NS], a2[NS];
  load_coefs(bc, ac, b0, b1, b2, a1, a2);

  const float4* __restrict__ gsrc =
      reinterpret_cast<const float4*>(x) + (size_t)blockIdx.x * 256 * LQ;

  // one deep burst: 16 linear loads (4KB contiguous per instruction per block)
  float4 ld[16];
#pragma unroll
  for (int k = 0; k < 16; ++k) ld[k] = gsrc[t + 256 * k];
#pragma unroll
  for (int k = 0; k < 16; ++k) {
    const int m = t + 256 * k;
    sbuf[slot_of(m >> 4, m & 15)] = ld[k];
  }
  __syncthreads();

  float s1[NS] = {0.f, 0.f, 0.f, 0.f};
  float s2[NS] = {0.f, 0.f, 0.f, 0.f};
#pragma unroll
  for (int q = 0; q < LQ; ++q) adv4(sbuf[slot_of(t, q)], CO, s1, s2);

  float* __restrict__ vp = vbuf + ((size_t)blockIdx.x * 256 + t) * NSTATE;
  *reinterpret_cast<float4*>(vp)     = make_float4(s1[0], s2[0], s1[1], s2[1]);
  *reinterpret_cast<float4*>(vp + 4) = make_float4(s1[2], s2[2], s1[3], s2[3]);
}

// ---------------------------------------------------------------------------
// Phase 2: Kogge-Stone affine scan. Wave 0 builds Ms[d] = (A^L)^(2^d)
// in-register via __shfl (14 squarings of the 8x8, one element per lane).
__global__ void k_scan_par(const float* __restrict__ bc,
                           const float* __restrict__ ac,
                           float* __restrict__ vbuf) {
  __shared__ float Ms[LOG2P][64];
  __shared__ float W[P][NSTATE + 1];  // stride 9: 2-way alias (free)

  const int t = threadIdx.x;  // P threads, block = one batch

  if (t < 64) {
    float b0[NS], b1[NS], b2[NS], a1[NS], a2[NS];
    load_coefs(bc, ac, b0, b1, b2, a1, a2);
    const int r = t >> 3, c = t & 7;
    float p1[NS] = {0.f, 0.f, 0.f, 0.f};
    float p2[NS] = {0.f, 0.f, 0.f, 0.f};
    if (c & 1) p2[c >> 1] = 1.0f; else p1[c >> 1] = 1.0f;
    (void)step_cascade(0.0f, CO, p1, p2);
    float m = (r & 1) ? p2[r >> 1] : p1[r >> 1];  // A element (r,c)
    for (int it = 0; it < LOG2L + LOG2P - 1; ++it) {
      float acc = 0.0f;
#pragma unroll
      for (int k = 0; k < NSTATE; ++k)
        acc = fmaf(__shfl(m, r * 8 + k), __shfl(m, k * 8 + c), acc);
      m = acc;
      if (it >= LOG2L - 1) Ms[it - (LOG2L - 1)][t] = m;
    }
  }

  float* __restrict__ vp = vbuf + ((size_t)blockIdx.x * P + t) * NSTATE;

  float w[NSTATE];
  {
    const float4 va = *reinterpret_cast<const float4*>(vp);
    const float4 vb = *reinterpret_cast<const float4*>(vp + 4);
    w[0] = va.x; w[1] = va.y; w[2] = va.z; w[3] = va.w;
    w[4] = vb.x; w[5] = vb.y; w[6] = vb.z; w[7] = vb.w;
  }
  __syncthreads();  // Ms ready

  for (int d = 0; d < LOG2P; ++d) {
#pragma unroll
    for (int r = 0; r < NSTATE; ++r) W[t][r] = w[r];
    __syncthreads();
    if (t >= (1 << d)) {
      const int src = t - (1 << d);
      float prev[NSTATE];
#pragma unroll
      for (int r = 0; r < NSTATE; ++r) prev[r] = W[src][r];
#pragma unroll
      for (int r = 0; r < NSTATE; ++r) {
        float acc = w[r];
#pragma unroll
        for (int k = 0; k < NSTATE; ++k)
          acc = fmaf(Ms[d][r * 8 + k], prev[k], acc);  // uniform addr: broadcast
        w[r] = acc;
      }
    }
    __syncthreads();
  }

  // exclusive shift: s_init(i) = (i==0 ? 0 : w_{i-1})
#pragma unroll
  for (int r = 0; r < NSTATE; ++r) W[t][r] = w[r];
  __syncthreads();
  float s[NSTATE];
  if (t == 0) {
#pragma unroll
    for (int r = 0; r < NSTATE; ++r) s[r] = 0.0f;
  } else {
#pragma unroll
    for (int r = 0; r < NSTATE; ++r) s[r] = W[t - 1][r];
  }
  *reinterpret_cast<float4*>(vp)     = make_float4(s[0], s[1], s[2], s[3]);
  *reinterpret_cast<float4*>(vp + 4) = make_float4(s[4], s[5], s[6], s[7]);
}

// ---------------------------------------------------------------------------
// Phase 3: replay from exact init. Burst-load linear -> LDS -> compute
// in-place (own slots) -> burst-store linear.
__global__ __launch_bounds__(256) void k_chunk_out(const float* __restrict__ x,
                                                   const float* __restrict__ bc,
                                                   const float* __restrict__ ac,
                                                   const float* __restrict__ sbuf_g,
                                                   float* __restrict__ out) {
  __shared__ float4 sbuf[256 * LQ];  // 64 KiB

  const int t = threadIdx.x;
  float b0[NS], b1[NS], b2[NS], a1[NS], a2[NS];
  load_coefs(bc, ac, b0, b1, b2, a1, a2);

  const float* __restrict__ sp =
      sbuf_g + ((size_t)blockIdx.x * 256 + t) * NSTATE;
  const float4 sa = *reinterpret_cast<const float4*>(sp);
  const float4 sb = *reinterpret_cast<const float4*>(sp + 4);
  float s1[NS] = {sa.x, sa.z, sb.x, sb.z};
  float s2[NS] = {sa.y, sa.w, sb.y, sb.w};

  const float4* __restrict__ gsrc =
      reinterpret_cast<const float4*>(x) + (size_t)blockIdx.x * 256 * LQ;
  float4* __restrict__ gdst =
      reinterpret_cast<float4*>(out) + (size_t)blockIdx.x * 256 * LQ;

  float4 ld[16];
#pragma unroll
  for (int k = 0; k < 16; ++k) ld[k] = gsrc[t + 256 * k];
#pragma unroll
  for (int k = 0; k < 16; ++k) {
    const int m = t + 256 * k;
    sbuf[slot_of(m >> 4, m & 15)] = ld[k];
  }
  __syncthreads();

#pragma unroll
  for (int q = 0; q < LQ; ++q) {
    const int s = slot_of(t, q);
    sbuf[s] = out4(sbuf[s], CO, s1, s2);  // in-place: own slots only
  }
  __syncthreads();

#pragma unroll
  for (int k = 0; k < 16; ++k) {
    const int m = t + 256 * k;
    gdst[m] = sbuf[slot_of(m >> 4, m & 15)];
  }
}

// ---------------------------------------------------------------------------
// Fallback (ws too small): one thread per batch, fully sequential but correct.
__global__ void k_naive(const float* __restrict__ x, const float* __restrict__ bc,
                        const float* __restrict__ ac, float* __restrict__ out) {
  const int bi = blockIdx.x * blockDim.x + threadIdx.x;
  if (bi >= BATCH) return;
  float b0[NS], b1[NS], b2[NS], a1[NS], a2[NS];
  load_coefs(bc, ac, b0, b1, b2, a1, a2);
  float s1[NS] = {0.f, 0.f, 0.f, 0.f};
  float s2[NS] = {0.f, 0.f, 0.f, 0.f};
  const float* __restrict__ xp = x + (size_t)bi * TLEN;
  float* __restrict__ op       = out + (size_t)bi * TLEN;
  for (int t = 0; t < TLEN; t += 4) {
    const float4 xv = *reinterpret_cast<const float4*>(xp + t);
    float4 y = out4(xv, CO, s1, s2);
    *reinterpret_cast<float4*>(op + t) = y;
  }
}

extern "C" void kernel_launch(void* const* d_in, const int* in_sizes, int n_in,
                              void* d_out, int out_size, void* d_ws, size_t ws_size,
                              hipStream_t stream) {
  const float* x  = (const float*)d_in[0];  // (B, T, 1)
  const float* bc = (const float*)d_in[1];  // (NS, 3)
  const float* ac = (const float*)d_in[2];  // (NS, 2)
  float* out = (float*)d_out;               // (B, T, 1)

  const size_t need = (size_t)BATCH * P * NSTATE * sizeof(float);
  if (ws_size < need) {
    k_naive<<<(BATCH + 255) / 256, 256, 0, stream>>>(x, bc, ac, out);
    return;
  }
  float* vbuf = (float*)d_ws;  // BATCH*P*8 floats

  k_chunk_state<<<(BATCH * P) / 256, 256, 0, stream>>>(x, bc, ac, vbuf);
  k_scan_par<<<BATCH, P, 0, stream>>>(bc, ac, vbuf);
  k_chunk_out<<<(BATCH * P) / 256, 256, 0, stream>>>(x, bc, ac, vbuf, out);
}